// Round 7
// baseline (7453.513 us; speedup 1.0000x reference)
//
#include <hip/hip_runtime.h>
#include <hip/hip_bf16.h>

typedef short short8 __attribute__((ext_vector_type(8)));
typedef float f32x4 __attribute__((ext_vector_type(4)));
typedef int   i32x4 __attribute__((ext_vector_type(4)));   // asm-tie-safe 16B vector

// ---- workspace layout (bytes) ----
#define OFF_U   0x0UL        // U bf16 [1024][1024]        2 MiB
#define OFF_W   0x200000UL   // W bf16 [1024][512]         1 MiB
#define OFF_PRE 0x300000UL   // pre bf16 [t=512][b=128][i=1024]  128 MiB
#define OFF_H0  0x8300000UL  // h buf0 bf16 [128][1024]    256 KiB
#define OFF_H1  0x8340000UL  // h buf1 bf16 [128][1024]    256 KiB
#define OFF_CNT 0x8380000UL  // flags uint[8 clusters][32] (one 128B line per cluster)

static __device__ __forceinline__ unsigned short f2bf(float f) {
  return __builtin_bit_cast(unsigned short, __float2bfloat16(f));
}
static __device__ __forceinline__ float bf2f(unsigned short u) {
  unsigned int v = (unsigned int)u << 16;
  return __builtin_bit_cast(float, v);
}
static __device__ __forceinline__ unsigned int pack2(float a, float b) {
  return (unsigned int)f2bf(a) | ((unsigned int)f2bf(b) << 16);
}
static __device__ __forceinline__ float fast_tanh(float x) {
  float xc = fminf(fmaxf(x, -10.f), 10.f);
  float e2 = __expf(2.f * xc);
  return 1.f - 2.f * __builtin_amdgcn_rcpf(e2 + 1.f);
}

// ---------------- fp32 -> bf16 bulk convert ----------------
__global__ __launch_bounds__(256) void cvt_bf16(const float* __restrict__ in,
                                                unsigned short* __restrict__ out, int n4) {
  int idx = blockIdx.x * 256 + threadIdx.x;
  if (idx < n4) {
    float4 v = *(const float4*)&in[idx * 4];
    uint2 p; p.x = pack2(v.x, v.y); p.y = pack2(v.z, v.w);
    *(uint2*)&out[idx * 4] = p;
  }
}

// ---------------- pre = gather(emb,x) @ W^T   (stored [t][b][i], bf16, NO bias) --------
__global__ __launch_bounds__(256) void pre_gemm(const int* __restrict__ x,
                                                const float* __restrict__ emb,
                                                const unsigned short* __restrict__ Wbf,
                                                unsigned short* __restrict__ pre) {
  const int t   = blockIdx.y;           // 0..511
  const int n0  = blockIdx.x * 128;     // i offset
  const int tid = threadIdx.x;
  const int lane = tid & 63, w = tid >> 6;
  const int q = lane >> 4, l15 = lane & 15;

  __shared__ unsigned short Alds[128][72];  // +8 pad
  __shared__ unsigned short Blds[128][72];
  __shared__ int tok[128];
  if (tid < 128) tok[tid] = x[tid * 512 + t];   // x[b][t]
  __syncthreads();

  f32x4 acc[4][4];
  #pragma unroll
  for (int a = 0; a < 4; ++a)
    #pragma unroll
    for (int b = 0; b < 4; ++b) acc[a][b] = {0.f, 0.f, 0.f, 0.f};

  const int wm = (w & 1) * 64, wn = (w >> 1) * 64;

  for (int k0 = 0; k0 < 512; k0 += 64) {
    #pragma unroll
    for (int it = 0; it < 8; ++it) {
      int idx = it * 256 + tid;
      int r = idx >> 4, c4 = (idx & 15) * 4;
      float4 v = *(const float4*)&emb[tok[r] * 512 + k0 + c4];
      uint2 p; p.x = pack2(v.x, v.y); p.y = pack2(v.z, v.w);
      *(uint2*)&Alds[r][c4] = p;
    }
    #pragma unroll
    for (int it = 0; it < 4; ++it) {
      int idx = it * 256 + tid;
      int r = idx >> 3, c8 = (idx & 7) * 8;
      *(int4*)&Blds[r][c8] = *(const int4*)&Wbf[(n0 + r) * 512 + k0 + c8];
    }
    __syncthreads();
    #pragma unroll
    for (int kt = 0; kt < 2; ++kt) {
      short8 af[4], bfr[4];
      #pragma unroll
      for (int mt = 0; mt < 4; ++mt) af[mt]  = *(const short8*)&Alds[wm + mt*16 + l15][kt*32 + q*8];
      #pragma unroll
      for (int nt = 0; nt < 4; ++nt) bfr[nt] = *(const short8*)&Blds[wn + nt*16 + l15][kt*32 + q*8];
      #pragma unroll
      for (int mt = 0; mt < 4; ++mt)
        #pragma unroll
        for (int nt = 0; nt < 4; ++nt)
          acc[mt][nt] = __builtin_amdgcn_mfma_f32_16x16x32_bf16(af[mt], bfr[nt], acc[mt][nt], 0, 0, 0);
    }
    __syncthreads();
  }
  #pragma unroll
  for (int mt = 0; mt < 4; ++mt) {
    int brow = wm + mt * 16 + q * 4;
    #pragma unroll
    for (int nt = 0; nt < 4; ++nt) {
      int i = n0 + wn + nt * 16 + l15;
      #pragma unroll
      for (int r = 0; r < 4; ++r)
        pre[(t * 128 + brow + r) * 1024 + i] = f2bf(acc[mt][nt][r]);
    }
  }
}

// ---- slow poll (proven round-7/9): sc1 probes, spin until all 8 flags >= tt ----
static __device__ __forceinline__ void poll_flags(const unsigned int* fp, unsigned int tt,
                                                  bool pact) {
  unsigned int va, vb;
  asm volatile("global_load_dword %0, %1, off sc1" : "=v"(va) : "v"(fp));
  for (;;) {
    asm volatile("global_load_dword %0, %1, off sc1\n\ts_waitcnt vmcnt(1)"
                 : "=v"(vb) : "v"(fp));
    unsigned int x = pact ? va : tt;
    if (__ballot(x < tt) == 0) break;       // va is complete (vmcnt(1) retired it)
    asm volatile("global_load_dword %0, %1, off sc1\n\ts_waitcnt vmcnt(1)"
                 : "=v"(va) : "v"(fp));
    x = pact ? vb : tt;
    if (__ballot(x < tt) == 0) break;
  }
  // UB fix: drain the dangling poll load NOW, while va/vb are still live.
  asm volatile("s_waitcnt vmcnt(0)");
}

// ---------------- persistent recurrence ----------------
// Round-12 = round-11c structure + XCD-SCOPE (sc0) fast path for h/flag traffic.
// Insight: clusters are XCD-local (cluster = bid&7 = XCD under round-robin,
// m09-verified), yet round-9/11 paid device-scope (sc1 -> MALL, ~1.2-1.5k cy RT)
// for every h/flag hop. sc0 (SE scope) loads bypass the per-CU L1 and are
// served by the XCD L2 (~200 cy RT) -- 5x cheaper per hop.
// Correctness does NOT depend on the (undefined) wg->XCD mapping:
//  * Producers DUAL-STORE h and flags to the same address: sc1 first (fresh at
//    MALL, device-visible), then sc0 (fresh dirty line in local L2). Identical
//    data -> any ordering/eviction still leaves every reader a fresh copy.
//  * Consumers load sc0 and validate via the bit14 phase tags (freshness proof
//    per 2 bytes). Bounded retry (2000 iters) then STICKY escalation to sc1
//    loads (reads MALL where the sc1 dual-store guarantees fresh data). Same
//    for the flag poll. No unbounded spin exists -> hang-proof; worst case is
//    one ~0.2ms timeout per wg then round-9 speed.
// Everything else identical to round-11c: 2-deep pre pipeline (P0/P1, vmcnt(1)
// discipline -- now load-bearing: at ~0.6us steps the ~900cy pre HBM latency
// would otherwise surface), 3 barriers/step, own-slice h in regs (pk), bit14
// tags tag(t)=((t>>1)&1)^1, poll UB fix. t=511 stores tag 0 (raw) into h0.
__global__ __launch_bounds__(512, 2) void recurrence(const unsigned short* __restrict__ Ubf,
                                                     const unsigned short* __restrict__ pre,
                                                     const float* __restrict__ Wb,
                                                     const float* __restrict__ Ub,
                                                     unsigned short* __restrict__ h0buf,
                                                     unsigned short* __restrict__ h1buf,
                                                     unsigned int* __restrict__ cnt) {
  const int c   = blockIdx.x & 7;        // cluster == XCD (round-robin dispatch)
  const int s   = blockIdx.x >> 3;       // i-slice
  const int tid = threadIdx.x;
  const int lane = tid & 63, wv = tid >> 6;
  const int q = lane >> 4, l15 = lane & 15;
  const int ibase = s * 128 + wv * 16;   // this wave's 16 i-rows
  const int bglob = c * 16;

  __shared__ unsigned short hlds[16][1032];   // [b][k], +8 pad

  // U A-fragments: 32 k-tiles, pinned resident (128 regs)
  short8 A[32];
  {
    const unsigned short* Up = Ubf + (ibase + l15) * 1024 + q * 8;
    #pragma unroll
    for (int kt = 0; kt < 32; ++kt) A[kt] = *(const short8*)(Up + kt * 32);
  }
  #pragma unroll
  for (int kt = 0; kt < 32; ++kt) asm volatile("" : "+v"(A[kt]));  // forbid remat

  float4 bias;
  {
    int i0b = ibase + q * 4;
    float4 wb = *(const float4*)&Wb[i0b];
    float4 ub = *(const float4*)&Ub[i0b];
    bias = make_float4(wb.x + ub.x, wb.y + ub.y, wb.z + ub.z, wb.w + ub.w);
  }

  unsigned int* fbase = cnt + c * 32;             // this cluster's 128B flag line
  const bool pact = (lane < 8) && (lane != s);    // poll participation (skip own)
  const unsigned int* fpoll = fbase + (lane & 7);
  unsigned int* fmine = fbase + s;
  const int sb = tid >> 7;              // staging row 0..3
  const int sk = (tid & 127) * 8;       // staging col (shorts)
  const bool notown = (sk >> 7) != s;   // this thread's 4 chunks are remote-slice
  const int i0 = ibase + q * 4;         // this thread's 4 own i-values
  const unsigned short* prebase = pre + (size_t)(bglob + l15) * 1024 + i0;

  // own-slice h values live in regs between steps; h_{-1} = 0
  uint2 pk; pk.x = 0u; pk.y = 0u;

  bool slowp = false;   // sticky: poll escalated to sc1 (per-thread, wv0 only)
  bool slows = false;   // sticky: stage escalated to sc1 (per-thread)

  // ---- pre pipeline prologue: pre(0) -> P0 (waited), pre(1) -> P1 (in flight)
  uint2 P0, P1;
  {
    const unsigned short* pp0 = prebase;
    const unsigned short* pp1 = prebase + 131072;
    asm volatile("global_load_dwordx2 %0, %1, off" : "=v"(P0) : "v"(pp0));
    asm volatile("global_load_dwordx2 %0, %1, off" : "=v"(P1) : "v"(pp1));
    asm volatile("s_waitcnt vmcnt(1)");   // P0 complete (retires any older too)
    asm volatile("" : "+v"(P0));          // order P0 reads after the wait
  }

  auto body = [&](int t, uint2& Pcur, uint2& Pnxt) {
    const unsigned short* hprev = (t & 1) ? h1buf : h0buf;
    unsigned short* hnew        = (t & 1) ? h0buf : h1buf;
    const unsigned int et = (t == 0) ? 0u
                          : (((((t - 1) >> 1) & 1) ^ 1) ? 0x40004000u : 0u);
    const unsigned int tm = (((t >> 1) & 1) ^ 1) ? 0x40004000u : 0u;  // tag(t)

    if (t > 0) {
      if (wv == 0) {
        const unsigned int tt = (unsigned int)t;
        if (!slowp) {
          // fast poll: sc0 probes served by the XCD L2
          unsigned int va, vb; int tries = 0; bool got = false;
          asm volatile("global_load_dword %0, %1, off sc0" : "=v"(va) : "v"(fpoll));
          for (;;) {
            asm volatile("global_load_dword %0, %1, off sc0\n\ts_waitcnt vmcnt(1)"
                         : "=v"(vb) : "v"(fpoll));
            unsigned int x = pact ? va : tt;
            if (__ballot(x < tt) == 0) { got = true; break; }
            if (++tries > 2000) break;    // ~0.5Mcy: never fires on jitter
            asm volatile("global_load_dword %0, %1, off sc0\n\ts_waitcnt vmcnt(1)"
                         : "=v"(va) : "v"(fpoll));
            x = pact ? vb : tt;
            if (__ballot(x < tt) == 0) { got = true; break; }
          }
          asm volatile("s_waitcnt vmcnt(0)");   // drain dangling probe (UB fix)
          if (!got) slowp = true;               // sticky escalation
        }
        if (slowp) poll_flags(fpoll, tt, pact); // proven sc1 poll (fresh at MALL)
      }
      __syncthreads();   // broadcast poll success (barrier a)
    }

    // ---- stage phase: issue h loads (sc0 fast / sc1 escalated), decode pre,
    //      issue pre(t+2), vmcnt(1), tag-validate, write LDS
    const unsigned short* hp = hprev + (size_t)(bglob + sb) * 1024 + sk;
    i32x4 r0, r1, r2, r3;
    if (notown) {
      if (slows) {
        asm volatile(
          "global_load_dwordx4 %0, %4, off sc1\n\t"
          "global_load_dwordx4 %1, %5, off sc1\n\t"
          "global_load_dwordx4 %2, %6, off sc1\n\t"
          "global_load_dwordx4 %3, %7, off sc1"
          : "=&v"(r0), "=&v"(r1), "=&v"(r2), "=&v"(r3)
          : "v"(hp), "v"(hp + 4 * 1024), "v"(hp + 8 * 1024), "v"(hp + 12 * 1024));
      } else {
        asm volatile(
          "global_load_dwordx4 %0, %4, off sc0\n\t"
          "global_load_dwordx4 %1, %5, off sc0\n\t"
          "global_load_dwordx4 %2, %6, off sc0\n\t"
          "global_load_dwordx4 %3, %7, off sc0"
          : "=&v"(r0), "=&v"(r1), "=&v"(r2), "=&v"(r3)
          : "v"(hp), "v"(hp + 4 * 1024), "v"(hp + 8 * 1024), "v"(hp + 12 * 1024));
      }
    }
    // decode pre(t) from Pcur (value complete; read BEFORE reissuing Pcur)
    float p0 = bf2f((unsigned short)(Pcur.x & 0xffff));
    float p1 = bf2f((unsigned short)(Pcur.x >> 16));
    float p2 = bf2f((unsigned short)(Pcur.y & 0xffff));
    float p3 = bf2f((unsigned short)(Pcur.y >> 16));
    {
      int tp = (t + 2 < 512) ? (t + 2) : 510;     // clamp: dup load, unused
      const unsigned short* pp = prebase + (size_t)tp * 131072;
      asm volatile("global_load_dwordx2 %0, %1, off" : "=v"(Pcur) : "v"(pp));
    }
    // retire everything older than pre(t+2): h stage loads, pre(t+1),
    // dangling h/flag stores. pre(t+2) stays in flight.
    asm volatile("s_waitcnt vmcnt(1)");
    asm volatile("" : "+v"(Pnxt));        // order next body's decode after wait
    if (notown) {
      asm volatile("" : "+v"(r0));        // one tied ext_vector op per stmt
      asm volatile("" : "+v"(r1));
      asm volatile("" : "+v"(r2));
      asm volatile("" : "+v"(r3));
      i32x4 d0, d1, d2, d3;
      int tries = 0;
      for (;;) {
        // decode == check: XOR by expected tag; any bit14 left set => stale
        d0 = r0 ^ (int)et;
        d1 = r1 ^ (int)et;
        d2 = r2 ^ (int)et;
        d3 = r3 ^ (int)et;
        i32x4 o = d0 | d1 | d2 | d3;
        unsigned int bad = (unsigned int)(o.x | o.y | o.z | o.w) & 0x40004000u;
        if (bad == 0) break;
        if (++tries > 2000) slows = true;    // sticky escalation
        if (slows) {
          asm volatile(
            "global_load_dwordx4 %0, %4, off sc1\n\t"
            "global_load_dwordx4 %1, %5, off sc1\n\t"
            "global_load_dwordx4 %2, %6, off sc1\n\t"
            "global_load_dwordx4 %3, %7, off sc1\n\t"
            "s_waitcnt vmcnt(0)"
            : "=&v"(r0), "=&v"(r1), "=&v"(r2), "=&v"(r3)
            : "v"(hp), "v"(hp + 4 * 1024), "v"(hp + 8 * 1024), "v"(hp + 12 * 1024));
        } else {
          asm volatile(
            "global_load_dwordx4 %0, %4, off sc0\n\t"
            "global_load_dwordx4 %1, %5, off sc0\n\t"
            "global_load_dwordx4 %2, %6, off sc0\n\t"
            "global_load_dwordx4 %3, %7, off sc0\n\t"
            "s_waitcnt vmcnt(0)"
            : "=&v"(r0), "=&v"(r1), "=&v"(r2), "=&v"(r3)
            : "v"(hp), "v"(hp + 4 * 1024), "v"(hp + 8 * 1024), "v"(hp + 12 * 1024));
        }
      }
      *(i32x4*)&hlds[sb][sk]      = d0;
      *(i32x4*)&hlds[sb + 4][sk]  = d1;
      *(i32x4*)&hlds[sb + 8][sk]  = d2;
      *(i32x4*)&hlds[sb + 12][sk] = d3;
    }
    *(uint2*)&hlds[l15][i0] = pk;         // own slice from regs (raw, t=0: zeros)
    __syncthreads();   // hlds fully staged (barrier b)

    f32x4 acc0 = {0.f, 0.f, 0.f, 0.f}, acc1 = {0.f, 0.f, 0.f, 0.f};
    #pragma unroll
    for (int kt = 0; kt < 32; kt += 2) {
      short8 b0 = *(const short8*)&hlds[l15][kt * 32 + q * 8];
      short8 b1 = *(const short8*)&hlds[l15][kt * 32 + 32 + q * 8];
      acc0 = __builtin_amdgcn_mfma_f32_16x16x32_bf16(A[kt],     b0, acc0, 0, 0, 0);
      acc1 = __builtin_amdgcn_mfma_f32_16x16x32_bf16(A[kt + 1], b1, acc1, 0, 0, 0);
    }

    // epilogue: D col=lane&15 -> batch, row=4q+r -> i
    float x0 = acc0[0] + acc1[0] + p0 + bias.x;
    float x1 = acc0[1] + acc1[1] + p1 + bias.y;
    float x2 = acc0[2] + acc1[2] + p2 + bias.z;
    float x3 = acc0[3] + acc1[3] + p3 + bias.w;
    pk.x = pack2(fast_tanh(x0), fast_tanh(x1));
    pk.y = pack2(fast_tanh(x2), fast_tanh(x3));
    {
      uint2 pkt; pkt.x = pk.x ^ tm; pkt.y = pk.y ^ tm;
      unsigned short* dst = hnew + (size_t)(bglob + l15) * 1024 + i0;
      // DUAL store, same addr/data: sc1 (fresh at MALL for any-scope readers)
      // then sc0 (fresh dirty line in the XCD L2 for fast-path readers).
      asm volatile("global_store_dwordx2 %0, %1, off sc1\n\t"
                   "global_store_dwordx2 %0, %1, off sc0"
                   : : "v"(dst), "v"(pkt));   // no drain: tags self-validate;
                                              // retired by next stage's vmcnt(1)
    }
    __syncthreads();   // all waves issued h stores + finished hlds reads (barrier d)
    if (tid == 0) {
      unsigned int tv = (unsigned int)(t + 1);
      asm volatile("global_store_dword %0, %1, off sc1\n\t"
                   "global_store_dword %0, %1, off sc0"
                   : : "v"(fmine), "v"(tv));
    }
  };

  #pragma unroll 1
  for (int t = 0; t < 512; t += 2) {
    body(t,     P0, P1);
    body(t + 1, P1, P0);
  }
}

// ---------------- final: sigmoid(h_T @ V^T + Vb) ----------------
__global__ __launch_bounds__(64) void final_out(const unsigned short* __restrict__ hT,
                                                const float* __restrict__ Vw,
                                                const float* __restrict__ Vb,
                                                float* __restrict__ out) {
  int b = blockIdx.x, lane = threadIdx.x;
  float sum = 0.f;
  #pragma unroll
  for (int k = 0; k < 16; ++k) {
    int i = k * 64 + lane;
    sum += bf2f(hT[b * 1024 + i]) * Vw[i];
  }
  #pragma unroll
  for (int off = 32; off; off >>= 1) sum += __shfl_down(sum, off);
  if (lane == 0) out[b] = 1.f / (1.f + expf(-(sum + Vb[0])));
}

extern "C" void kernel_launch(void* const* d_in, const int* in_sizes, int n_in,
                              void* d_out, int out_size, void* d_ws, size_t ws_size,
                              hipStream_t stream) {
  const int*   x   = (const int*)d_in[0];
  const float* emb = (const float*)d_in[1];
  const float* W_w = (const float*)d_in[2];
  const float* W_b = (const float*)d_in[3];
  const float* U_w = (const float*)d_in[4];
  const float* U_b = (const float*)d_in[5];
  const float* V_w = (const float*)d_in[6];
  const float* V_b = (const float*)d_in[7];
  float* out = (float*)d_out;
  char*  ws  = (char*)d_ws;

  unsigned short* Ubf = (unsigned short*)(ws + OFF_U);
  unsigned short* Wbf = (unsigned short*)(ws + OFF_W);
  unsigned short* pre = (unsigned short*)(ws + OFF_PRE);
  unsigned short* h0  = (unsigned short*)(ws + OFF_H0);
  unsigned short* h1  = (unsigned short*)(ws + OFF_H1);
  unsigned int*   cnt = (unsigned int*)(ws + OFF_CNT);

  // zero h0 (h_{-1}, tag 0 == valid zeros) + h1 + flags. Re-runs every replay.
  // Kernel-launch acquire invalidates per-XCD L2s, so no stale lines survive
  // a replay into the sc0 fast path.
  hipMemsetAsync(ws + OFF_H0, 0, (OFF_CNT - OFF_H0) + 0x1000, stream);

  cvt_bf16<<<1024, 256, 0, stream>>>(U_w, Ubf, 1024 * 1024 / 4);
  cvt_bf16<<<512, 256, 0, stream>>>(W_w, Wbf, 1024 * 512 / 4);

  pre_gemm<<<dim3(8, 512), 256, 0, stream>>>(x, emb, Wbf, pre);

  void* args[] = {&Ubf, &pre, &W_b, &U_b, &h0, &h1, &cnt};
  hipLaunchCooperativeKernel((void*)recurrence, dim3(64), dim3(512), args, 0, stream);

  // t=511 writes h0 with tag(511)=0 (raw bf16)
  final_out<<<128, 64, 0, stream>>>(h0, V_w, V_b, out);
}

// Round 8
// 2330.985 us; speedup vs baseline: 3.1976x; 3.1976x over previous
//
#include <hip/hip_runtime.h>
#include <hip/hip_bf16.h>

typedef short short8 __attribute__((ext_vector_type(8)));
typedef float f32x4 __attribute__((ext_vector_type(4)));
typedef int   i32x4 __attribute__((ext_vector_type(4)));   // asm-tie-safe 16B vector

// ---- workspace layout (bytes) ----
#define OFF_U   0x0UL        // U bf16 [1024][1024]        2 MiB
#define OFF_W   0x200000UL   // W bf16 [1024][512]         1 MiB
#define OFF_PRE 0x300000UL   // pre bf16 [t=512][b=128][i=1024]  128 MiB
#define OFF_H0  0x8300000UL  // h buf0 bf16 [128][1024]    256 KiB
#define OFF_H1  0x8340000UL  // h buf1 bf16 [128][1024]    256 KiB
#define OFF_CNT 0x8380000UL  // flags uint[8 clusters][32] (one 128B line per cluster)

static __device__ __forceinline__ unsigned short f2bf(float f) {
  return __builtin_bit_cast(unsigned short, __float2bfloat16(f));
}
static __device__ __forceinline__ float bf2f(unsigned short u) {
  unsigned int v = (unsigned int)u << 16;
  return __builtin_bit_cast(float, v);
}
static __device__ __forceinline__ unsigned int pack2(float a, float b) {
  return (unsigned int)f2bf(a) | ((unsigned int)f2bf(b) << 16);
}
static __device__ __forceinline__ float fast_tanh(float x) {
  float xc = fminf(fmaxf(x, -10.f), 10.f);
  float e2 = __expf(2.f * xc);
  return 1.f - 2.f * __builtin_amdgcn_rcpf(e2 + 1.f);
}

// ---------------- fp32 -> bf16 bulk convert ----------------
__global__ __launch_bounds__(256) void cvt_bf16(const float* __restrict__ in,
                                                unsigned short* __restrict__ out, int n4) {
  int idx = blockIdx.x * 256 + threadIdx.x;
  if (idx < n4) {
    float4 v = *(const float4*)&in[idx * 4];
    uint2 p; p.x = pack2(v.x, v.y); p.y = pack2(v.z, v.w);
    *(uint2*)&out[idx * 4] = p;
  }
}

// ---------------- pre = gather(emb,x) @ W^T   (stored [t][b][i], bf16, NO bias) --------
__global__ __launch_bounds__(256) void pre_gemm(const int* __restrict__ x,
                                                const float* __restrict__ emb,
                                                const unsigned short* __restrict__ Wbf,
                                                unsigned short* __restrict__ pre) {
  const int t   = blockIdx.y;           // 0..511
  const int n0  = blockIdx.x * 128;     // i offset
  const int tid = threadIdx.x;
  const int lane = tid & 63, w = tid >> 6;
  const int q = lane >> 4, l15 = lane & 15;

  __shared__ unsigned short Alds[128][72];  // +8 pad
  __shared__ unsigned short Blds[128][72];
  __shared__ int tok[128];
  if (tid < 128) tok[tid] = x[tid * 512 + t];   // x[b][t]
  __syncthreads();

  f32x4 acc[4][4];
  #pragma unroll
  for (int a = 0; a < 4; ++a)
    #pragma unroll
    for (int b = 0; b < 4; ++b) acc[a][b] = {0.f, 0.f, 0.f, 0.f};

  const int wm = (w & 1) * 64, wn = (w >> 1) * 64;

  for (int k0 = 0; k0 < 512; k0 += 64) {
    #pragma unroll
    for (int it = 0; it < 8; ++it) {
      int idx = it * 256 + tid;
      int r = idx >> 4, c4 = (idx & 15) * 4;
      float4 v = *(const float4*)&emb[tok[r] * 512 + k0 + c4];
      uint2 p; p.x = pack2(v.x, v.y); p.y = pack2(v.z, v.w);
      *(uint2*)&Alds[r][c4] = p;
    }
    #pragma unroll
    for (int it = 0; it < 4; ++it) {
      int idx = it * 256 + tid;
      int r = idx >> 3, c8 = (idx & 7) * 8;
      *(int4*)&Blds[r][c8] = *(const int4*)&Wbf[(n0 + r) * 512 + k0 + c8];
    }
    __syncthreads();
    #pragma unroll
    for (int kt = 0; kt < 2; ++kt) {
      short8 af[4], bfr[4];
      #pragma unroll
      for (int mt = 0; mt < 4; ++mt) af[mt]  = *(const short8*)&Alds[wm + mt*16 + l15][kt*32 + q*8];
      #pragma unroll
      for (int nt = 0; nt < 4; ++nt) bfr[nt] = *(const short8*)&Blds[wn + nt*16 + l15][kt*32 + q*8];
      #pragma unroll
      for (int mt = 0; mt < 4; ++mt)
        #pragma unroll
        for (int nt = 0; nt < 4; ++nt)
          acc[mt][nt] = __builtin_amdgcn_mfma_f32_16x16x32_bf16(af[mt], bfr[nt], acc[mt][nt], 0, 0, 0);
    }
    __syncthreads();
  }
  #pragma unroll
  for (int mt = 0; mt < 4; ++mt) {
    int brow = wm + mt * 16 + q * 4;
    #pragma unroll
    for (int nt = 0; nt < 4; ++nt) {
      int i = n0 + wn + nt * 16 + l15;
      #pragma unroll
      for (int r = 0; r < 4; ++r)
        pre[(t * 128 + brow + r) * 1024 + i] = f2bf(acc[mt][nt][r]);
    }
  }
}

// ---- poll: spin on this cluster's 8 flags until all >= tt (round-7/9 proven) ----
// NOTE: caller may have other loads in flight (speculative stage); the first
// vmcnt(1) rotation retires them along the way (harmless, they were issued
// earlier and overlap the poll's own RT). Exit drains vmcnt(0) (UB fix).
static __device__ __forceinline__ void poll_flags(const unsigned int* fp, unsigned int tt,
                                                  bool pact) {
  unsigned int va, vb;
  asm volatile("global_load_dword %0, %1, off sc1" : "=v"(va) : "v"(fp));
  for (;;) {
    asm volatile("global_load_dword %0, %1, off sc1\n\ts_waitcnt vmcnt(1)"
                 : "=v"(vb) : "v"(fp));
    unsigned int x = pact ? va : tt;
    if (__ballot(x < tt) == 0) break;       // va is complete (vmcnt(1) retired it)
    asm volatile("global_load_dword %0, %1, off sc1\n\ts_waitcnt vmcnt(1)"
                 : "=v"(va) : "v"(fp));
    x = pact ? vb : tt;
    if (__ballot(x < tt) == 0) break;
  }
  asm volatile("s_waitcnt vmcnt(0)");
}

// ---------------- persistent recurrence ----------------
// Round-13 = round-11c + SPECULATIVE STAGE: the h stage loads are issued at the
// TOP of the step, before/parallel with the flag poll, so their ~1 MALL RT
// hides under the poll's ~1.5 RT instead of following it serially.
//  * Safety: the bit14 phase tags (tag(t)=((t>>1)&1)^1) validate freshness of
//    every 2 bytes AFTER the poll barrier; stale chunks (speculative load beat
//    the producer's store to the MALL) retry -- costing exactly what the old
//    protocol paid unconditionally. ABA-safe: buf[(t-1)&1] cannot be
//    overwritten until step t+1 stores, which require poll(t+1), which
//    requires OUR flag(t) -- impossible while we are staging step t.
//  * vmcnt discipline: pre(t+2) is issued AFTER the poll (wave 0's poll
//    rotation would otherwise eat a fresh ~900cy HBM load); the post-barrier
//    vmcnt(1) then retires stage loads + pre(t+1) + dangling stores and leaves
//    only pre(t+2) in flight. Wave 0's poll drains its own stage loads mid-
//    poll (overlapped, harmless).
//  * Round-7 lesson kept: all cross-wg traffic is sc1 (device scope). sc0
//    proved non-coherent for this pattern (round-12: 7x regression).
//  * 64 wgs, XCD-local clusters (cluster = bid&7; round-10: breaking this
//    costs 2x). 3 barriers/step, own-slice h in regs (pk), 2-deep pre
//    pipeline, poll UB fix. t=511 stores tag 0 (raw) into h0.
__global__ __launch_bounds__(512, 2) void recurrence(const unsigned short* __restrict__ Ubf,
                                                     const unsigned short* __restrict__ pre,
                                                     const float* __restrict__ Wb,
                                                     const float* __restrict__ Ub,
                                                     unsigned short* __restrict__ h0buf,
                                                     unsigned short* __restrict__ h1buf,
                                                     unsigned int* __restrict__ cnt) {
  const int c   = blockIdx.x & 7;        // cluster == XCD (round-robin dispatch)
  const int s   = blockIdx.x >> 3;       // i-slice
  const int tid = threadIdx.x;
  const int lane = tid & 63, wv = tid >> 6;
  const int q = lane >> 4, l15 = lane & 15;
  const int ibase = s * 128 + wv * 16;   // this wave's 16 i-rows
  const int bglob = c * 16;

  __shared__ unsigned short hlds[16][1032];   // [b][k], +8 pad

  // U A-fragments: 32 k-tiles, pinned resident (128 regs)
  short8 A[32];
  {
    const unsigned short* Up = Ubf + (ibase + l15) * 1024 + q * 8;
    #pragma unroll
    for (int kt = 0; kt < 32; ++kt) A[kt] = *(const short8*)(Up + kt * 32);
  }
  #pragma unroll
  for (int kt = 0; kt < 32; ++kt) asm volatile("" : "+v"(A[kt]));  // forbid remat

  float4 bias;
  {
    int i0b = ibase + q * 4;
    float4 wb = *(const float4*)&Wb[i0b];
    float4 ub = *(const float4*)&Ub[i0b];
    bias = make_float4(wb.x + ub.x, wb.y + ub.y, wb.z + ub.z, wb.w + ub.w);
  }

  unsigned int* fbase = cnt + c * 32;             // this cluster's 128B flag line
  const bool pact = (lane < 8) && (lane != s);    // poll participation (skip own)
  const unsigned int* fpoll = fbase + (lane & 7);
  unsigned int* fmine = fbase + s;
  const int sb = tid >> 7;              // staging row 0..3
  const int sk = (tid & 127) * 8;       // staging col (shorts)
  const bool notown = (sk >> 7) != s;   // this thread's 4 chunks are remote-slice
  const int i0 = ibase + q * 4;         // this thread's 4 own i-values
  const unsigned short* prebase = pre + (size_t)(bglob + l15) * 1024 + i0;

  // own-slice h values live in regs between steps; h_{-1} = 0
  uint2 pk; pk.x = 0u; pk.y = 0u;

  // ---- pre pipeline prologue: pre(0) -> P0 (waited), pre(1) -> P1 (in flight)
  uint2 P0, P1;
  {
    const unsigned short* pp0 = prebase;
    const unsigned short* pp1 = prebase + 131072;
    asm volatile("global_load_dwordx2 %0, %1, off" : "=v"(P0) : "v"(pp0));
    asm volatile("global_load_dwordx2 %0, %1, off" : "=v"(P1) : "v"(pp1));
    asm volatile("s_waitcnt vmcnt(1)");   // P0 complete (retires any older too)
    asm volatile("" : "+v"(P0));          // order P0 reads after the wait
  }

  auto body = [&](int t, uint2& Pcur, uint2& Pnxt) {
    const unsigned short* hprev = (t & 1) ? h1buf : h0buf;
    unsigned short* hnew        = (t & 1) ? h0buf : h1buf;
    const unsigned int et = (t == 0) ? 0u
                          : (((((t - 1) >> 1) & 1) ^ 1) ? 0x40004000u : 0u);
    const unsigned int tm = (((t >> 1) & 1) ^ 1) ? 0x40004000u : 0u;  // tag(t)

    // ---- SPECULATIVE stage issue: h loads race the poll; tags validate later
    const unsigned short* hp = hprev + (size_t)(bglob + sb) * 1024 + sk;
    i32x4 r0, r1, r2, r3;
    if (notown) {
      asm volatile(
        "global_load_dwordx4 %0, %4, off sc1\n\t"
        "global_load_dwordx4 %1, %5, off sc1\n\t"
        "global_load_dwordx4 %2, %6, off sc1\n\t"
        "global_load_dwordx4 %3, %7, off sc1"
        : "=&v"(r0), "=&v"(r1), "=&v"(r2), "=&v"(r3)
        : "v"(hp), "v"(hp + 4 * 1024), "v"(hp + 8 * 1024), "v"(hp + 12 * 1024));
    }

    if (t > 0) {
      if (wv == 0) poll_flags(fpoll, (unsigned int)t, pact);
      __syncthreads();   // broadcast poll success (barrier a)
    }

    // decode pre(t) from Pcur (complete since step t-1's wait), then reissue
    float p0 = bf2f((unsigned short)(Pcur.x & 0xffff));
    float p1 = bf2f((unsigned short)(Pcur.x >> 16));
    float p2 = bf2f((unsigned short)(Pcur.y & 0xffff));
    float p3 = bf2f((unsigned short)(Pcur.y >> 16));
    {
      int tp = (t + 2 < 512) ? (t + 2) : 510;     // clamp: dup load, unused
      const unsigned short* pp = prebase + (size_t)tp * 131072;
      asm volatile("global_load_dwordx2 %0, %1, off" : "=v"(Pcur) : "v"(pp));
    }
    // retire everything older than pre(t+2): stage loads (had the whole poll
    // to complete), pre(t+1), dangling h/flag stores. pre(t+2) stays in flight.
    asm volatile("s_waitcnt vmcnt(1)");
    asm volatile("" : "+v"(Pnxt));        // order next body's decode after wait
    if (notown) {
      asm volatile("" : "+v"(r0));        // one tied ext_vector op per stmt
      asm volatile("" : "+v"(r1));
      asm volatile("" : "+v"(r2));
      asm volatile("" : "+v"(r3));
      i32x4 d0, d1, d2, d3;
      for (;;) {
        // decode == check: XOR by expected tag; any bit14 left set => stale
        d0 = r0 ^ (int)et;
        d1 = r1 ^ (int)et;
        d2 = r2 ^ (int)et;
        d3 = r3 ^ (int)et;
        i32x4 o = d0 | d1 | d2 | d3;
        unsigned int bad = (unsigned int)(o.x | o.y | o.z | o.w) & 0x40004000u;
        if (bad == 0) break;
        // stale: speculative load beat the producer's store; reload (bounded
        // in practice -- poll already proved the producer issued its stores)
        asm volatile(
          "global_load_dwordx4 %0, %4, off sc1\n\t"
          "global_load_dwordx4 %1, %5, off sc1\n\t"
          "global_load_dwordx4 %2, %6, off sc1\n\t"
          "global_load_dwordx4 %3, %7, off sc1\n\t"
          "s_waitcnt vmcnt(0)"
          : "=&v"(r0), "=&v"(r1), "=&v"(r2), "=&v"(r3)
          : "v"(hp), "v"(hp + 4 * 1024), "v"(hp + 8 * 1024), "v"(hp + 12 * 1024));
      }
      *(i32x4*)&hlds[sb][sk]      = d0;
      *(i32x4*)&hlds[sb + 4][sk]  = d1;
      *(i32x4*)&hlds[sb + 8][sk]  = d2;
      *(i32x4*)&hlds[sb + 12][sk] = d3;
    }
    *(uint2*)&hlds[l15][i0] = pk;         // own slice from regs (raw, t=0: zeros)
    __syncthreads();   // hlds fully staged (barrier b)

    f32x4 acc0 = {0.f, 0.f, 0.f, 0.f}, acc1 = {0.f, 0.f, 0.f, 0.f};
    #pragma unroll
    for (int kt = 0; kt < 32; kt += 2) {
      short8 b0 = *(const short8*)&hlds[l15][kt * 32 + q * 8];
      short8 b1 = *(const short8*)&hlds[l15][kt * 32 + 32 + q * 8];
      acc0 = __builtin_amdgcn_mfma_f32_16x16x32_bf16(A[kt],     b0, acc0, 0, 0, 0);
      acc1 = __builtin_amdgcn_mfma_f32_16x16x32_bf16(A[kt + 1], b1, acc1, 0, 0, 0);
    }

    // epilogue: D col=lane&15 -> batch, row=4q+r -> i
    float x0 = acc0[0] + acc1[0] + p0 + bias.x;
    float x1 = acc0[1] + acc1[1] + p1 + bias.y;
    float x2 = acc0[2] + acc1[2] + p2 + bias.z;
    float x3 = acc0[3] + acc1[3] + p3 + bias.w;
    pk.x = pack2(fast_tanh(x0), fast_tanh(x1));
    pk.y = pack2(fast_tanh(x2), fast_tanh(x3));
    {
      uint2 pkt; pkt.x = pk.x ^ tm; pkt.y = pk.y ^ tm;
      unsigned short* dst = hnew + (size_t)(bglob + l15) * 1024 + i0;
      asm volatile("global_store_dwordx2 %0, %1, off sc1"
                   : : "v"(dst), "v"(pkt));   // no drain: tags self-validate;
                                              // retired by next step's vmcnt(1)
    }
    __syncthreads();   // all waves issued h stores + finished hlds reads (barrier d)
    if (tid == 0) {
      unsigned int tv = (unsigned int)(t + 1);
      asm volatile("global_store_dword %0, %1, off sc1" : : "v"(fmine), "v"(tv));
    }
  };

  #pragma unroll 1
  for (int t = 0; t < 512; t += 2) {
    body(t,     P0, P1);
    body(t + 1, P1, P0);
  }
}

// ---------------- final: sigmoid(h_T @ V^T + Vb) ----------------
__global__ __launch_bounds__(64) void final_out(const unsigned short* __restrict__ hT,
                                                const float* __restrict__ Vw,
                                                const float* __restrict__ Vb,
                                                float* __restrict__ out) {
  int b = blockIdx.x, lane = threadIdx.x;
  float sum = 0.f;
  #pragma unroll
  for (int k = 0; k < 16; ++k) {
    int i = k * 64 + lane;
    sum += bf2f(hT[b * 1024 + i]) * Vw[i];
  }
  #pragma unroll
  for (int off = 32; off; off >>= 1) sum += __shfl_down(sum, off);
  if (lane == 0) out[b] = 1.f / (1.f + expf(-(sum + Vb[0])));
}

extern "C" void kernel_launch(void* const* d_in, const int* in_sizes, int n_in,
                              void* d_out, int out_size, void* d_ws, size_t ws_size,
                              hipStream_t stream) {
  const int*   x   = (const int*)d_in[0];
  const float* emb = (const float*)d_in[1];
  const float* W_w = (const float*)d_in[2];
  const float* W_b = (const float*)d_in[3];
  const float* U_w = (const float*)d_in[4];
  const float* U_b = (const float*)d_in[5];
  const float* V_w = (const float*)d_in[6];
  const float* V_b = (const float*)d_in[7];
  float* out = (float*)d_out;
  char*  ws  = (char*)d_ws;

  unsigned short* Ubf = (unsigned short*)(ws + OFF_U);
  unsigned short* Wbf = (unsigned short*)(ws + OFF_W);
  unsigned short* pre = (unsigned short*)(ws + OFF_PRE);
  unsigned short* h0  = (unsigned short*)(ws + OFF_H0);
  unsigned short* h1  = (unsigned short*)(ws + OFF_H1);
  unsigned int*   cnt = (unsigned int*)(ws + OFF_CNT);

  // zero h0 (h_{-1}, tag 0 == valid zeros) + h1 + flags. Re-runs every replay.
  hipMemsetAsync(ws + OFF_H0, 0, (OFF_CNT - OFF_H0) + 0x1000, stream);

  cvt_bf16<<<1024, 256, 0, stream>>>(U_w, Ubf, 1024 * 1024 / 4);
  cvt_bf16<<<512, 256, 0, stream>>>(W_w, Wbf, 1024 * 512 / 4);

  pre_gemm<<<dim3(8, 512), 256, 0, stream>>>(x, emb, Wbf, pre);

  void* args[] = {&Ubf, &pre, &W_b, &U_b, &h0, &h1, &cnt};
  hipLaunchCooperativeKernel((void*)recurrence, dim3(64), dim3(512), args, 0, stream);

  // t=511 writes h0 with tag(511)=0 (raw bf16)
  final_out<<<128, 64, 0, stream>>>(h0, V_w, V_b, out);
}

// Round 10
// 2260.890 us; speedup vs baseline: 3.2967x; 1.0310x over previous
//
#include <hip/hip_runtime.h>
#include <hip/hip_bf16.h>

typedef short short8 __attribute__((ext_vector_type(8)));
typedef float f32x4 __attribute__((ext_vector_type(4)));
typedef int   i32x4 __attribute__((ext_vector_type(4)));   // asm-tie-safe 16B vector

// ---- workspace layout (bytes) ----
#define OFF_U   0x0UL        // U bf16 [1024][1024]        2 MiB
#define OFF_W   0x200000UL   // W bf16 [1024][512]         1 MiB
#define OFF_PRE 0x300000UL   // pre bf16 [t=512][b=128][i=1024]  128 MiB
#define OFF_H0  0x8300000UL  // h buf0 bf16 [128][1024]    256 KiB
#define OFF_H1  0x8340000UL  // h buf1 bf16 [128][1024]    256 KiB
#define OFF_CNT 0x8380000UL  // flags uint[8 clusters][64 wave-flags] (256B per cluster)

static __device__ __forceinline__ unsigned short f2bf(float f) {
  return __builtin_bit_cast(unsigned short, __float2bfloat16(f));
}
static __device__ __forceinline__ float bf2f(unsigned short u) {
  unsigned int v = (unsigned int)u << 16;
  return __builtin_bit_cast(float, v);
}
static __device__ __forceinline__ unsigned int pack2(float a, float b) {
  return (unsigned int)f2bf(a) | ((unsigned int)f2bf(b) << 16);
}
static __device__ __forceinline__ float fast_tanh(float x) {
  float xc = fminf(fmaxf(x, -10.f), 10.f);
  float e2 = __expf(2.f * xc);
  return 1.f - 2.f * __builtin_amdgcn_rcpf(e2 + 1.f);
}

// ---------------- fp32 -> bf16 bulk convert ----------------
__global__ __launch_bounds__(256) void cvt_bf16(const float* __restrict__ in,
                                                unsigned short* __restrict__ out, int n4) {
  int idx = blockIdx.x * 256 + threadIdx.x;
  if (idx < n4) {
    float4 v = *(const float4*)&in[idx * 4];
    uint2 p; p.x = pack2(v.x, v.y); p.y = pack2(v.z, v.w);
    *(uint2*)&out[idx * 4] = p;
  }
}

// ---------------- pre = gather(emb,x) @ W^T   (stored [t][b][i], bf16, NO bias) --------
__global__ __launch_bounds__(256) void pre_gemm(const int* __restrict__ x,
                                                const float* __restrict__ emb,
                                                const unsigned short* __restrict__ Wbf,
                                                unsigned short* __restrict__ pre) {
  const int t   = blockIdx.y;           // 0..511
  const int n0  = blockIdx.x * 128;     // i offset
  const int tid = threadIdx.x;
  const int lane = tid & 63, w = tid >> 6;
  const int q = lane >> 4, l15 = lane & 15;

  __shared__ unsigned short Alds[128][72];  // +8 pad
  __shared__ unsigned short Blds[128][72];
  __shared__ int tok[128];
  if (tid < 128) tok[tid] = x[tid * 512 + t];   // x[b][t]
  __syncthreads();

  f32x4 acc[4][4];
  #pragma unroll
  for (int a = 0; a < 4; ++a)
    #pragma unroll
    for (int b = 0; b < 4; ++b) acc[a][b] = {0.f, 0.f, 0.f, 0.f};

  const int wm = (w & 1) * 64, wn = (w >> 1) * 64;

  for (int k0 = 0; k0 < 512; k0 += 64) {
    #pragma unroll
    for (int it = 0; it < 8; ++it) {
      int idx = it * 256 + tid;
      int r = idx >> 4, c4 = (idx & 15) * 4;
      float4 v = *(const float4*)&emb[tok[r] * 512 + k0 + c4];
      uint2 p; p.x = pack2(v.x, v.y); p.y = pack2(v.z, v.w);
      *(uint2*)&Alds[r][c4] = p;
    }
    #pragma unroll
    for (int it = 0; it < 4; ++it) {
      int idx = it * 256 + tid;
      int r = idx >> 3, c8 = (idx & 7) * 8;
      *(int4*)&Blds[r][c8] = *(const int4*)&Wbf[(n0 + r) * 512 + k0 + c8];
    }
    __syncthreads();
    #pragma unroll
    for (int kt = 0; kt < 2; ++kt) {
      short8 af[4], bfr[4];
      #pragma unroll
      for (int mt = 0; mt < 4; ++mt) af[mt]  = *(const short8*)&Alds[wm + mt*16 + l15][kt*32 + q*8];
      #pragma unroll
      for (int nt = 0; nt < 4; ++nt) bfr[nt] = *(const short8*)&Blds[wn + nt*16 + l15][kt*32 + q*8];
      #pragma unroll
      for (int mt = 0; mt < 4; ++mt)
        #pragma unroll
        for (int nt = 0; nt < 4; ++nt)
          acc[mt][nt] = __builtin_amdgcn_mfma_f32_16x16x32_bf16(af[mt], bfr[nt], acc[mt][nt], 0, 0, 0);
    }
    __syncthreads();
  }
  #pragma unroll
  for (int mt = 0; mt < 4; ++mt) {
    int brow = wm + mt * 16 + q * 4;
    #pragma unroll
    for (int nt = 0; nt < 4; ++nt) {
      int i = n0 + wn + nt * 16 + l15;
      #pragma unroll
      for (int r = 0; r < 4; ++r)
        pre[(t * 128 + brow + r) * 1024 + i] = f2bf(acc[mt][nt][r]);
    }
  }
}

// ---- poll: spin until all 64 cluster wave-flags (minus own wg's 8) >= tt ----
// Same proven double-buffered vmcnt(1) rotation + exit drain (UB fix) as
// round-7/9; only the flag fan-out changed (per-WAVE flags, 64 lanes poll).
static __device__ __forceinline__ void poll_flags(const unsigned int* fp, unsigned int tt,
                                                  bool pact) {
  unsigned int va, vb;
  asm volatile("global_load_dword %0, %1, off sc1" : "=v"(va) : "v"(fp));
  for (;;) {
    asm volatile("global_load_dword %0, %1, off sc1\n\ts_waitcnt vmcnt(1)"
                 : "=v"(vb) : "v"(fp));
    unsigned int x = pact ? va : tt;
    if (__ballot(x < tt) == 0) break;       // va is complete (vmcnt(1) retired it)
    asm volatile("global_load_dword %0, %1, off sc1\n\ts_waitcnt vmcnt(1)"
                 : "=v"(va) : "v"(fp));
    x = pact ? vb : tt;
    if (__ballot(x < tt) == 0) break;
  }
  // UB fix: drain the dangling poll load NOW, while va/vb are still live.
  asm volatile("s_waitcnt vmcnt(0)");
}

// ---------------- persistent recurrence ----------------
// Round-15 = round-9 (the session-best proven kernel: 64 wgs, 8 XCD-local
// clusters x 8 wgs, flags + bit14 tags tag(t)=((t>>1)&1)^1, no producer
// drain, stage-once-after-poll, sc1-only, 2-buffer) + PER-WAVE FLAGS:
//  * OLD: one flag per wg, stored by tid0 after barrier d -- the barrier
//    existed only so one thread could vouch for all 8 waves. The flag thus
//    waited on the SLOWEST wave + a full-wg barrier every step.
//  * NEW: 64 flags per cluster (8 wgs x 8 waves). Each wave's lane 0 stores
//    its own flag right after the wave's h-store issue -- no barrier. The
//    poll checks 64 flags with 64 lanes (still one load/lane); own wg's 8
//    wave-flags are skipped (own waves are synced by barrier a instead).
//  * Safety: flag(w) = t+1 is stored after wave w's epilogue(t), which is
//    after its stage(t) loads retired (pre-barrier-b vmcnt(0)) -- so
//    poll(t+1) passing proves all readers of h(t-1) are done before anyone
//    overwrites buf[(t+1)&1]. Data arrival is still tag-validated, so the
//    flag/data race needs no store drain (round-9 invariant).
//  * Barriers per step: a (poll broadcast), b (staged), c (post-MFMA, before
//    epilogue's own-slice LDS rewrite). Barrier d is DELETED.
// Round-12 lesson kept: sc1 everywhere (sc0 not coherent cross-wg).
// Round-13 lesson kept: data loads issue strictly after the poll.
// t=511 stores tag 0 (raw) into h0 => final_out reads it untouched.
__global__ __launch_bounds__(512, 2) void recurrence(const unsigned short* __restrict__ Ubf,
                                                     const unsigned short* __restrict__ pre,
                                                     const float* __restrict__ Wb,
                                                     const float* __restrict__ Ub,
                                                     unsigned short* __restrict__ h0buf,
                                                     unsigned short* __restrict__ h1buf,
                                                     unsigned int* __restrict__ cnt) {
  const int c   = blockIdx.x & 7;        // cluster == XCD (round-robin dispatch)
  const int s   = blockIdx.x >> 3;       // i-slice
  const int tid = threadIdx.x;
  const int lane = tid & 63, wv = tid >> 6;
  const int q = lane >> 4, l15 = lane & 15;
  const int ibase = s * 128 + wv * 16;   // this wave's 16 i-rows
  const int bglob = c * 16;

  __shared__ unsigned short hlds[16][1032];   // [b][k], +8 pad

  // zero own-slice region of hlds (h_{-1} = 0; stage never writes own slice)
  {
    int r = tid >> 5;                 // 0..15
    int kk = (tid & 31) * 4;          // 0..124
    *(uint2*)&hlds[r][s * 128 + kk] = make_uint2(0u, 0u);
  }

  // U A-fragments: 32 k-tiles, pinned resident (128 regs)
  short8 A[32];
  {
    const unsigned short* Up = Ubf + (ibase + l15) * 1024 + q * 8;
    #pragma unroll
    for (int kt = 0; kt < 32; ++kt) A[kt] = *(const short8*)(Up + kt * 32);
  }
  #pragma unroll
  for (int kt = 0; kt < 32; ++kt) asm volatile("" : "+v"(A[kt]));  // forbid remat

  float4 bias;
  {
    int i0 = ibase + q * 4;
    float4 wb = *(const float4*)&Wb[i0];
    float4 ub = *(const float4*)&Ub[i0];
    bias = make_float4(wb.x + ub.x, wb.y + ub.y, wb.z + ub.z, wb.w + ub.w);
  }

  unsigned int* fbase = cnt + c * 64;             // 64 wave-flags per cluster
  const bool pact = (lane >> 3) != s;             // skip own wg's 8 wave-flags
  const unsigned int* fpoll = fbase + lane;       // one flag per lane
  unsigned int* fmine = fbase + s * 8 + wv;       // this wave's flag
  const int sb = tid >> 7;              // staging row 0..3
  const int sk = (tid & 127) * 8;       // staging col (shorts)
  const bool notown = (sk >> 7) != s;   // this thread's 4 chunks are remote-slice
  const unsigned short* prebase = pre + (size_t)(bglob + l15) * 1024 + ibase + q * 4;

  __syncthreads();   // own-slice zero visible before t=0 MFMA

  #pragma unroll 1
  for (int t = 0; t < 512; ++t) {
    // pre prefetch — asm so our manual vmcnt FIFO stays the only counter model
    uint2 pvr;
    {
      const unsigned short* pp = prebase + (size_t)t * 131072;
      asm volatile("global_load_dwordx2 %0, %1, off" : "=v"(pvr) : "v"(pp));
    }

    const unsigned short* hprev = (t & 1) ? h1buf : h0buf;
    unsigned short* hnew        = (t & 1) ? h0buf : h1buf;
    // expected tag on h_{t-1}'s shorts (t=0 reads memset zeros: tag 0, correct data)
    const unsigned int et = (t == 0) ? 0u
                          : (((((t - 1) >> 1) & 1) ^ 1) ? 0x40004000u : 0u);

    if (t > 0) {
      if (wv == 0) poll_flags(fpoll, (unsigned int)t, pact);
      __syncthreads();   // broadcast poll success (barrier a)
    }

    // stage remote slices of h[16][1024] -> LDS, loaded ONCE; tags validate the
    // flag-vs-data arrival race (retry only re-reads while stale — rare, short)
    {
      const unsigned short* hp = hprev + (size_t)(bglob + sb) * 1024 + sk;
      i32x4 d0, d1, d2, d3;
      if (notown) {
        for (;;) {
          i32x4 r0, r1, r2, r3;
          asm volatile(
            "global_load_dwordx4 %0, %4, off sc1\n\t"
            "global_load_dwordx4 %1, %5, off sc1\n\t"
            "global_load_dwordx4 %2, %6, off sc1\n\t"
            "global_load_dwordx4 %3, %7, off sc1\n\t"
            "s_waitcnt vmcnt(0)"
            : "=&v"(r0), "=&v"(r1), "=&v"(r2), "=&v"(r3)
            : "v"(hp), "v"(hp + 4 * 1024), "v"(hp + 8 * 1024), "v"(hp + 12 * 1024));
          // decode == check: XOR by expected tag; any bit14 left set => stale
          d0 = r0 ^ (int)et;
          d1 = r1 ^ (int)et;
          d2 = r2 ^ (int)et;
          d3 = r3 ^ (int)et;
          i32x4 o = d0 | d1 | d2 | d3;
          unsigned int bad = (unsigned int)(o.x | o.y | o.z | o.w) & 0x40004000u;
          if (bad == 0) break;
        }
        *(i32x4*)&hlds[sb][sk]      = d0;
        *(i32x4*)&hlds[sb + 4][sk]  = d1;
        *(i32x4*)&hlds[sb + 8][sk]  = d2;
        *(i32x4*)&hlds[sb + 12][sk] = d3;
      } else {
        asm volatile("s_waitcnt vmcnt(0)");   // drains pvr (+ dangling stores)
      }
    }
    __syncthreads();   // hlds fully staged (barrier b)

    f32x4 acc0 = {0.f, 0.f, 0.f, 0.f}, acc1 = {0.f, 0.f, 0.f, 0.f};
    #pragma unroll
    for (int kt = 0; kt < 32; kt += 2) {
      short8 b0 = *(const short8*)&hlds[l15][kt * 32 + q * 8];
      short8 b1 = *(const short8*)&hlds[l15][kt * 32 + 32 + q * 8];
      acc0 = __builtin_amdgcn_mfma_f32_16x16x32_bf16(A[kt],     b0, acc0, 0, 0, 0);
      acc1 = __builtin_amdgcn_mfma_f32_16x16x32_bf16(A[kt + 1], b1, acc1, 0, 0, 0);
    }
    __syncthreads();   // all waves done READING hlds before epilogue rewrites own slice (barrier c)

    // epilogue: D col=lane&15 -> batch, row=4q+r -> i
    float p0 = bf2f((unsigned short)(pvr.x & 0xffff));
    float p1 = bf2f((unsigned short)(pvr.x >> 16));
    float p2 = bf2f((unsigned short)(pvr.y & 0xffff));
    float p3 = bf2f((unsigned short)(pvr.y >> 16));
    float x0 = acc0[0] + acc1[0] + p0 + bias.x;
    float x1 = acc0[1] + acc1[1] + p1 + bias.y;
    float x2 = acc0[2] + acc1[2] + p2 + bias.z;
    float x3 = acc0[3] + acc1[3] + p3 + bias.w;
    uint2 pk;
    pk.x = pack2(fast_tanh(x0), fast_tanh(x1));
    pk.y = pack2(fast_tanh(x2), fast_tanh(x3));

    {
      const unsigned int tm = (((t >> 1) & 1) ^ 1) ? 0x40004000u : 0u;  // tag(t)
      const int i0 = ibase + q * 4;           // global i == own k index
      *(uint2*)&hlds[l15][i0] = pk;           // own-slice short-circuit (LDS, raw)
      uint2 pkt; pkt.x = pk.x ^ tm; pkt.y = pk.y ^ tm;
      unsigned short* dst = hnew + (size_t)(bglob + l15) * 1024 + i0;
      asm volatile("global_store_dwordx2 %0, %1, off sc1"
                   : : "v"(dst), "v"(pkt));   // no drain: tags self-validate;
                                              // retired by next stage's vmcnt(0)
    }
    // PER-WAVE flag: no barrier -- this wave vouches only for itself. Its
    // stage(t) reads retired before barrier b; its h stores are issued above
    // (program order in the same FIFO); tags cover the flag/data race.
    if (lane == 0) {
      unsigned int tv = (unsigned int)(t + 1);
      asm volatile("global_store_dword %0, %1, off sc1" : : "v"(fmine), "v"(tv));
    }
  }
}

// ---------------- final: sigmoid(h_T @ V^T + Vb) ----------------
__global__ __launch_bounds__(64) void final_out(const unsigned short* __restrict__ hT,
                                                const float* __restrict__ Vw,
                                                const float* __restrict__ Vb,
                                                float* __restrict__ out) {
  int b = blockIdx.x, lane = threadIdx.x;
  float sum = 0.f;
  #pragma unroll
  for (int k = 0; k < 16; ++k) {
    int i = k * 64 + lane;
    sum += bf2f(hT[b * 1024 + i]) * Vw[i];
  }
  #pragma unroll
  for (int off = 32; off; off >>= 1) sum += __shfl_down(sum, off);
  if (lane == 0) out[b] = 1.f / (1.f + expf(-(sum + Vb[0])));
}

extern "C" void kernel_launch(void* const* d_in, const int* in_sizes, int n_in,
                              void* d_out, int out_size, void* d_ws, size_t ws_size,
                              hipStream_t stream) {
  const int*   x   = (const int*)d_in[0];
  const float* emb = (const float*)d_in[1];
  const float* W_w = (const float*)d_in[2];
  const float* W_b = (const float*)d_in[3];
  const float* U_w = (const float*)d_in[4];
  const float* U_b = (const float*)d_in[5];
  const float* V_w = (const float*)d_in[6];
  const float* V_b = (const float*)d_in[7];
  float* out = (float*)d_out;
  char*  ws  = (char*)d_ws;

  unsigned short* Ubf = (unsigned short*)(ws + OFF_U);
  unsigned short* Wbf = (unsigned short*)(ws + OFF_W);
  unsigned short* pre = (unsigned short*)(ws + OFF_PRE);
  unsigned short* h0  = (unsigned short*)(ws + OFF_H0);
  unsigned short* h1  = (unsigned short*)(ws + OFF_H1);
  unsigned int*   cnt = (unsigned int*)(ws + OFF_CNT);

  // zero h0 (h_{-1}, tag 0 == valid zeros) + h1 + all 512 wave-flags.
  // Re-runs every graph replay.
  hipMemsetAsync(ws + OFF_H0, 0, (OFF_CNT - OFF_H0) + 0x1000, stream);

  cvt_bf16<<<1024, 256, 0, stream>>>(U_w, Ubf, 1024 * 1024 / 4);
  cvt_bf16<<<512, 256, 0, stream>>>(W_w, Wbf, 1024 * 512 / 4);

  pre_gemm<<<dim3(8, 512), 256, 0, stream>>>(x, emb, Wbf, pre);

  void* args[] = {&Ubf, &pre, &W_b, &U_b, &h0, &h1, &cnt};
  hipLaunchCooperativeKernel((void*)recurrence, dim3(64), dim3(512), args, 0, stream);

  // t=511 writes h0 with tag(511)=0 (raw bf16)
  final_out<<<128, 64, 0, stream>>>(h0, V_w, V_b, out);
}